// Round 27
// baseline (101.728 us; speedup 1.0000x reference)
//
#include <hip/hip_runtime.h>
#include <math.h>

#define N_SAMP 4096
#define NS     7
#define DT_F   1e-5f
#define B0_F   80.0f
#define T2_F   1.0f
#define SW_F   1000.0f
#define TWO_PI 6.2831853071795864769f
#define EIG_T  640   // 10 waves: exactly max pairs/round (C(5,2)=10)

// ws layout (floats): Vc 0..3432 | Uc 4096..7099 | lam 16384..16512 |
//                     wc 49280..52352 | ab(int) 52352..55424 | hl 55424..58496 |
//                     sr 58496..61568 | si 61568..64640
// out (f32, 24576): ReFID [0,4096) | time [4096,8192) |
//                   Re shifted spec [8192,16384) | freq [16384,24576)

// Sector eigensolver, two-sided Jacobi, sparsity-aware 21-round colored sweep
__global__ __launch_bounds__(EIG_T) void k_eig(const float* __restrict__ h,
                                               float* __restrict__ Vc,
                                               float* __restrict__ Uc,
                                               float* __restrict__ lam_out) {
    const int nsz_[8]   = {1, 7, 21, 35, 35, 21, 7, 1};
    const int nbase_[8] = {0, 1, 8, 29, 64, 99, 120, 127};
    const int cum2_[8]  = {0, 1, 50, 491, 1716, 2941, 3382, 3431};
    const int offsU_[8] = {0, 0, 7, 154, 889, 2114, 2849, 2996}; // s>=1
    const int s    = blockIdx.x;
    const int ns   = nsz_[s];
    const int base = nbase_[s];
    const int tid  = threadIdx.x;
    const int wave = tid >> 6;
    const int lane = tid & 63;

    __shared__ float As[36 * 37];
    __shared__ float Vs[36 * 37];
    __shared__ int   st[36];
    __shared__ int   stm1[36];
    __shared__ int   inv[128];
    __shared__ float hs[49];
    __shared__ int   ppt2[21 * 12];
    __shared__ int   cnt2[21];

    const int ksm1 = (s >= 1) ? nsz_[s - 1] : 0;

    if (tid < 49) hs[tid] = h[tid];
    if (tid < 21) cnt2[tid] = 0;
    if (tid == 0) {
        int cnt = 0;
        for (int r = 0; r < 128; ++r) if (__popc(r) == s) st[cnt++] = r;
    }
    if (tid == 1 && s >= 1) {
        int cnt = 0;
        for (int r = 0; r < 128; ++r) if (__popc(r) == s - 1) stm1[cnt++] = r;
    }
    if (tid < 128 && __popc(tid) == s) {
        int cnt = 0;
        for (int r = 0; r < 128; ++r) { if (r == tid) break; if (__popc(r) == s) ++cnt; }
        inv[tid] = cnt;
    }
    for (int t = tid; t < 36 * 37; t += EIG_T) { As[t] = 0.f; Vs[t] = 0.f; }
    __syncthreads();

    if (ns > 1) {
        const int off_[7] = {0, 6, 11, 15, 18, 20, 0};
        for (int r = tid; r < 128; r += EIG_T) {
            if (__popc(r) == s) {
                for (int i = 0; i < 6; ++i) {
                    if (!((r >> i) & 1)) continue;
                    for (int j = i + 1; j < 7; ++j) {
                        if ((r >> j) & 1) continue;
                        int rid = off_[i] + (j - i - 1);
                        int prt = r ^ ((1 << i) | (1 << j));
                        int slot = atomicAdd(&cnt2[rid], 1);
                        ppt2[rid * 12 + slot] = (inv[r] << 8) | inv[prt];
                    }
                }
            }
        }
    }

    for (int t = tid; t < ns * ns; t += EIG_T) {
        int i = t / ns, j = t % ns;
        int r = st[i], c = st[j];
        float val = 0.f;
        if (r == c) {
            float acc = 0.f;
            for (int a = 0; a < 7; ++a) {
                float za = ((r >> (6 - a)) & 1) ? -0.5f : 0.5f;
                acc += B0_F * hs[a * 7 + a] * za;
                for (int b = a + 1; b < 7; ++b) {
                    float zb = ((r >> (6 - b)) & 1) ? -0.5f : 0.5f;
                    acc += hs[a * 7 + b] * za * zb;
                }
            }
            val = TWO_PI * acc;
        } else {
            int x = r ^ c;
            if (__popc(x) == 2) {
                int u = 31 - __clz(x);
                int v = __ffs(x) - 1;
                if (((r >> u) & 1) != ((r >> v) & 1))
                    val = TWO_PI * 0.5f * hs[(6 - u) * 7 + (6 - v)];
            }
        }
        As[i * 37 + j] = val;
    }
    for (int i = tid; i < ns; i += EIG_T) Vs[i * 37 + i] = 1.f;
    __syncthreads();

    if (ns > 1) {
        for (int t = 0; t < 21; ++t) {
            int npr = cnt2[t];
            float c0 = 1.f, s0 = 0.f;
            int   pq0 = -1;
            if (wave < npr) {
                int pq = ppt2[t * 12 + wave];
                int p = pq >> 8, q = pq & 255;
                float app = As[p * 37 + p];
                float aqq = As[q * 37 + q];
                float apq = As[p * 37 + q];
                float c = 1.f, sn = 0.f;
                if (fabsf(apq) >= 1e-30f) {
                    float tau = (aqq - app) / (2.f * apq);
                    float tt  = copysignf(1.f / (fabsf(tau) + sqrtf(1.f + tau * tau)), tau);
                    c  = rsqrtf(1.f + tt * tt);
                    sn = tt * c;
                }
                c0 = c; s0 = sn; pq0 = pq;
                if (lane < ns) {
                    float ap = As[p * 37 + lane], aq = As[q * 37 + lane];
                    As[p * 37 + lane] = c * ap - sn * aq;
                    As[q * 37 + lane] = sn * ap + c * aq;
                    float vp = Vs[p * 37 + lane], vq = Vs[q * 37 + lane];
                    Vs[p * 37 + lane] = c * vp - sn * vq;
                    Vs[q * 37 + lane] = sn * vp + c * vq;
                }
            }
            __syncthreads();
            if (pq0 >= 0) {
                int p = pq0 >> 8, q = pq0 & 255;
                if (lane < ns) {
                    float ap = As[lane * 37 + p], aq = As[lane * 37 + q];
                    As[lane * 37 + p] = c0 * ap - s0 * aq;
                    As[lane * 37 + q] = s0 * ap + c0 * aq;
                }
            }
            __syncthreads();
        }
    }

    for (int i = tid; i < ns; i += EIG_T) lam_out[base + i] = As[i * 37 + i];
    for (int t = tid; t < ns * ns; t += EIG_T) {
        int a = t / ns, k = t - (t / ns) * ns;
        Vc[cum2_[s] + t] = Vs[a * 37 + k];
    }
    if (s >= 1) {
        for (int t = tid; t < ns * ksm1; t += EIG_T) {
            int a = t / ksm1, i = t - (t / ksm1) * ksm1;
            int rr = stm1[i];
            float uval = 0.f;
#pragma unroll
            for (int p = 0; p < 7; ++p)
                if (!((rr >> p) & 1)) uval += Vs[a * 37 + inv[rr + (1 << p)]];
            Uc[offsU_[s] + t] = uval;
        }
    }
}

// Compact W + per-entry spectral constants: hl = dLam*DT/2, sigma = rho^4096.
__global__ __launch_bounds__(128) void k_mwc(const float* __restrict__ Vc,
                                             const float* __restrict__ Uc,
                                             const float* __restrict__ lam,
                                             float* __restrict__ wc,
                                             int* __restrict__ ab,
                                             float* __restrict__ hl,
                                             float* __restrict__ sr,
                                             float* __restrict__ si) {
    const int n1_[7]   = {1, 7, 21, 35, 35, 21, 7};
    const int n2_[7]   = {7, 21, 35, 35, 21, 7, 1};
    const int offs_[7] = {0, 7, 154, 889, 2114, 2849, 2996};
    const int nb1_[7]  = {0, 1, 8, 29, 64, 99, 120};
    const int nb2_[7]  = {1, 8, 29, 64, 99, 120, 127};
    const int cum2_[7] = {0, 1, 50, 491, 1716, 2941, 3382};
    int e = blockIdx.x * 128 + threadIdx.x;
    if (e >= 3072) return;
    if (e >= 3003) { wc[e] = 0.f; ab[e] = 0; hl[e] = 0.f; sr[e] = 0.f; si[e] = 0.f; return; }
    int t = 0;
#pragma unroll
    for (int u = 1; u < 7; ++u) if (e >= offs_[u]) t = u;
    int loc = e - offs_[t];
    int n1 = n1_[t], n2 = n2_[t];
    int i = loc / n2;
    int j = loc - i * n2;
    const float* va = &Vc[cum2_[t] + i * n1];
    const float* ub = &Uc[offs_[t] + j * n1];
    float acc = 0.f;
    for (int k = 0; k < n1; ++k) acc += va[k] * ub[k];
    int a = nb1_[t] + i, b = nb2_[t] + j;
    wc[e] = 0.5f * acc * acc;
    ab[e] = (a << 7) | b;
    float dl = lam[a] - lam[b];
    hl[e] = dl * (DT_F * 0.5f);
    const float TT = (float)N_SAMP * DT_F;        // 0.04096
    const float E  = expf(-TT / T2_F);
    float s2, c2;
    sincosf(dl * TT, &s2, &c2);
    sr[e] = E * c2;
    si[e] = E * s2;
}

// FID via phasor recurrence (real part only -> out[0..4096))
__global__ __launch_bounds__(256) void k_fid(const float* __restrict__ wc,
                                             const int* __restrict__ ab,
                                             const float* __restrict__ lam,
                                             float* __restrict__ out) {
    __shared__ float2 cb0[128], dd[128];
    __shared__ float  lred[4][16];
    const int n0  = blockIdx.x * 8;
    const int tid = threadIdx.x;
    const float t0 = (float)n0 * DT_F;
    if (tid < 128) {
        float sn, cs;
        sincosf(lam[tid] * t0, &sn, &cs);
        cb0[tid] = make_float2(cs, -sn);
        sincosf(lam[tid] * DT_F, &sn, &cs);
        dd[tid] = make_float2(cs, -sn);
    }
    __syncthreads();

    float ar0=0,ar1=0,ar2=0,ar3=0,ar4=0,ar5=0,ar6=0,ar7=0;
    float ai0=0,ai1=0,ai2=0,ai3=0,ai4=0,ai5=0,ai6=0,ai7=0;
#pragma unroll 4
    for (int i = 0; i < 12; ++i) {
        int e = i * 256 + tid;
        float w = wc[e];
        int pq = ab[e];
        int a = pq >> 7, b = pq & 127;
        float2 ca = cb0[a], cbv = cb0[b];
        float2 da = dd[a],  db  = dd[b];
        float zr = ca.x * cbv.x + ca.y * cbv.y;
        float zi = ca.x * cbv.y - ca.y * cbv.x;
        float fr = da.x * db.x + da.y * db.y;
        float fi = da.x * db.y - da.y * db.x;
        ar0 += w * zr; ai0 += w * zi; { float tr = zr*fr - zi*fi; zi = zr*fi + zi*fr; zr = tr; }
        ar1 += w * zr; ai1 += w * zi; { float tr = zr*fr - zi*fi; zi = zr*fi + zi*fr; zr = tr; }
        ar2 += w * zr; ai2 += w * zi; { float tr = zr*fr - zi*fi; zi = zr*fi + zi*fr; zr = tr; }
        ar3 += w * zr; ai3 += w * zi; { float tr = zr*fr - zi*fi; zi = zr*fi + zi*fr; zr = tr; }
        ar4 += w * zr; ai4 += w * zi; { float tr = zr*fr - zi*fi; zi = zr*fi + zi*fr; zr = tr; }
        ar5 += w * zr; ai5 += w * zi; { float tr = zr*fr - zi*fi; zi = zr*fi + zi*fr; zr = tr; }
        ar6 += w * zr; ai6 += w * zi; { float tr = zr*fr - zi*fi; zi = zr*fi + zi*fr; zr = tr; }
        ar7 += w * zr; ai7 += w * zi;
    }

    const int wave = tid >> 6, lane = tid & 63;
    float acc[16] = {ar0,ai0,ar1,ai1,ar2,ai2,ar3,ai3,ar4,ai4,ar5,ai5,ar6,ai6,ar7,ai7};
#pragma unroll 16
    for (int v = 0; v < 16; ++v) {
        float x = acc[v];
        for (int off = 32; off > 0; off >>= 1) x += __shfl_down(x, off);
        if (lane == 0) lred[wave][v] = x;
    }
    __syncthreads();
    if (tid < 16) {
        float x = lred[0][tid] + lred[1][tid] + lred[2][tid] + lred[3][tid];
        int jj = tid >> 1, c = tid & 1;
        int n = n0 + jj;
        float ap = expf(-(DT_F / T2_F) * (float)n);
        x *= ap;
        if (c == 0) out[n] = x;
    }
}

// Closed-form spectrum: spec[k] = sum_e wc*(1 - sigma*(-1)^K)/(1 - rho*omega_k).
// Denominator via half-angle identity (no cancellation):
//   Re = A + 2B sin^2(phi/2), Im = -2B sin(phi/2)cos(phi/2), phi/2 = hl - piK/8192
//   A = 1-exp(-DT/T2) (exact const), B = exp(-DT/T2).
// 8 lanes per k; 32 k per block; 256 blocks. Also writes time/freq axes.
__global__ __launch_bounds__(256) void k_spec(const float* __restrict__ wc,
                                              const float* __restrict__ hl,
                                              const float* __restrict__ sr,
                                              const float* __restrict__ si,
                                              float* __restrict__ out) {
    __shared__ float lwc[3072], lhl[3072], lsr[3072], lsi[3072];
    const int tid = threadIdx.x;
    for (int e = tid; e < 3072; e += 256) {
        lwc[e] = wc[e]; lhl[e] = hl[e]; lsr[e] = sr[e]; lsi[e] = si[e];
    }
    __syncthreads();
    const int kk = blockIdx.x * 32 + (tid >> 3);    // 0..8191
    const int l8 = tid & 7;
    const int K  = (kk + 4096) & 8191;
    const float pk  = (3.14159265358979f / 8192.0f) * (float)K;
    const float skf = (K & 1) ? -1.f : 1.f;
    const float A = 9.99995000e-06f;                // 1 - exp(-1e-5)
    const float B = 0.99999000005f;                 // exp(-1e-5)
    float acc = 0.f;
    for (int e = l8; e < 3072; e += 8) {
        float ph = lhl[e] - pk;
        float sh, ch;
        __sincosf(ph, &sh, &ch);
        float dr = A + 2.f * B * sh * sh;
        float di = -2.f * B * sh * ch;
        float nr = 1.f - skf * lsr[e];
        float ni = -skf * lsi[e];
        float num = nr * dr + ni * di;
        float den = dr * dr + di * di;
        acc += lwc[e] * num / den;
    }
#pragma unroll
    for (int off = 4; off > 0; off >>= 1) acc += __shfl_down(acc, off, 8);
    if (l8 == 0) {
        out[8192 + kk] = acc;
        out[16384 + kk] = -0.5f * SW_F + (float)kk * (SW_F / (float)(2 * N_SAMP - 1));
        if (kk < N_SAMP)
            out[4096 + kk] = (float)kk * ((N_SAMP / SW_F) / (float)(N_SAMP - 1));
    }
}

extern "C" void kernel_launch(void* const* d_in, const int* in_sizes, int n_in,
                              void* d_out, int out_size, void* d_ws, size_t ws_size,
                              hipStream_t stream) {
    const float* h = (const float*)d_in[0];
    float* out = (float*)d_out;
    float* ws  = (float*)d_ws;

    float*  Vc   = ws;
    float*  Uc   = ws + 4096;
    float*  lam  = ws + 16384;
    float*  wc   = ws + 49280;
    int*    ab   = (int*)(ws + 52352);
    float*  hl   = ws + 55424;
    float*  sr   = ws + 58496;
    float*  si   = ws + 61568;

    k_eig<<<8, EIG_T, 0, stream>>>(h, Vc, Uc, lam);
    k_mwc<<<24, 128, 0, stream>>>(Vc, Uc, lam, wc, ab, hl, sr, si);
    k_fid<<<512, 256, 0, stream>>>(wc, ab, lam, out);
    k_spec<<<256, 256, 0, stream>>>(wc, hl, sr, si, out);
}

// Round 28
// 67.796 us; speedup vs baseline: 1.5005x; 1.5005x over previous
//
#include <hip/hip_runtime.h>
#include <math.h>

#define N_SAMP 4096
#define NS     7
#define DT_F   1e-5f
#define B0_F   80.0f
#define T2_F   1.0f
#define SW_F   1000.0f
#define TWO_PI 6.2831853071795864769f
#define EIG_T  640   // 10 waves: exactly max pairs/round (C(5,2)=10)

// ws layout (floats): Vc 0..3432 | Uc 4096..7099 | lam 16384..16512 |
//                     wc 49280..52352 | ab(int) 52352..55424 | hl 55424..58496 |
//                     sr 58496..61568 | si 61568..64640
// out (f32, 24576): ReFID [0,4096) | time [4096,8192) |
//                   Re shifted spec [8192,16384) | freq [16384,24576)

// Sector eigensolver, two-sided Jacobi, sparsity-aware 21-round colored sweep
__global__ __launch_bounds__(EIG_T) void k_eig(const float* __restrict__ h,
                                               float* __restrict__ Vc,
                                               float* __restrict__ Uc,
                                               float* __restrict__ lam_out) {
    const int nsz_[8]   = {1, 7, 21, 35, 35, 21, 7, 1};
    const int nbase_[8] = {0, 1, 8, 29, 64, 99, 120, 127};
    const int cum2_[8]  = {0, 1, 50, 491, 1716, 2941, 3382, 3431};
    const int offsU_[8] = {0, 0, 7, 154, 889, 2114, 2849, 2996}; // s>=1
    const int s    = blockIdx.x;
    const int ns   = nsz_[s];
    const int base = nbase_[s];
    const int tid  = threadIdx.x;
    const int wave = tid >> 6;
    const int lane = tid & 63;

    __shared__ float As[36 * 37];
    __shared__ float Vs[36 * 37];
    __shared__ int   st[36];
    __shared__ int   stm1[36];
    __shared__ int   inv[128];
    __shared__ float hs[49];
    __shared__ int   ppt2[21 * 12];
    __shared__ int   cnt2[21];

    const int ksm1 = (s >= 1) ? nsz_[s - 1] : 0;

    if (tid < 49) hs[tid] = h[tid];
    if (tid < 21) cnt2[tid] = 0;
    if (tid == 0) {
        int cnt = 0;
        for (int r = 0; r < 128; ++r) if (__popc(r) == s) st[cnt++] = r;
    }
    if (tid == 1 && s >= 1) {
        int cnt = 0;
        for (int r = 0; r < 128; ++r) if (__popc(r) == s - 1) stm1[cnt++] = r;
    }
    if (tid < 128 && __popc(tid) == s) {
        int cnt = 0;
        for (int r = 0; r < 128; ++r) { if (r == tid) break; if (__popc(r) == s) ++cnt; }
        inv[tid] = cnt;
    }
    for (int t = tid; t < 36 * 37; t += EIG_T) { As[t] = 0.f; Vs[t] = 0.f; }
    __syncthreads();

    if (ns > 1) {
        const int off_[7] = {0, 6, 11, 15, 18, 20, 0};
        for (int r = tid; r < 128; r += EIG_T) {
            if (__popc(r) == s) {
                for (int i = 0; i < 6; ++i) {
                    if (!((r >> i) & 1)) continue;
                    for (int j = i + 1; j < 7; ++j) {
                        if ((r >> j) & 1) continue;
                        int rid = off_[i] + (j - i - 1);
                        int prt = r ^ ((1 << i) | (1 << j));
                        int slot = atomicAdd(&cnt2[rid], 1);
                        ppt2[rid * 12 + slot] = (inv[r] << 8) | inv[prt];
                    }
                }
            }
        }
    }

    for (int t = tid; t < ns * ns; t += EIG_T) {
        int i = t / ns, j = t % ns;
        int r = st[i], c = st[j];
        float val = 0.f;
        if (r == c) {
            float acc = 0.f;
            for (int a = 0; a < 7; ++a) {
                float za = ((r >> (6 - a)) & 1) ? -0.5f : 0.5f;
                acc += B0_F * hs[a * 7 + a] * za;
                for (int b = a + 1; b < 7; ++b) {
                    float zb = ((r >> (6 - b)) & 1) ? -0.5f : 0.5f;
                    acc += hs[a * 7 + b] * za * zb;
                }
            }
            val = TWO_PI * acc;
        } else {
            int x = r ^ c;
            if (__popc(x) == 2) {
                int u = 31 - __clz(x);
                int v = __ffs(x) - 1;
                if (((r >> u) & 1) != ((r >> v) & 1))
                    val = TWO_PI * 0.5f * hs[(6 - u) * 7 + (6 - v)];
            }
        }
        As[i * 37 + j] = val;
    }
    for (int i = tid; i < ns; i += EIG_T) Vs[i * 37 + i] = 1.f;
    __syncthreads();

    if (ns > 1) {
        for (int t = 0; t < 21; ++t) {
            int npr = cnt2[t];
            float c0 = 1.f, s0 = 0.f;
            int   pq0 = -1;
            if (wave < npr) {
                int pq = ppt2[t * 12 + wave];
                int p = pq >> 8, q = pq & 255;
                float app = As[p * 37 + p];
                float aqq = As[q * 37 + q];
                float apq = As[p * 37 + q];
                float c = 1.f, sn = 0.f;
                if (fabsf(apq) >= 1e-30f) {
                    float tau = (aqq - app) / (2.f * apq);
                    float tt  = copysignf(1.f / (fabsf(tau) + sqrtf(1.f + tau * tau)), tau);
                    c  = rsqrtf(1.f + tt * tt);
                    sn = tt * c;
                }
                c0 = c; s0 = sn; pq0 = pq;
                if (lane < ns) {
                    float ap = As[p * 37 + lane], aq = As[q * 37 + lane];
                    As[p * 37 + lane] = c * ap - sn * aq;
                    As[q * 37 + lane] = sn * ap + c * aq;
                    float vp = Vs[p * 37 + lane], vq = Vs[q * 37 + lane];
                    Vs[p * 37 + lane] = c * vp - sn * vq;
                    Vs[q * 37 + lane] = sn * vp + c * vq;
                }
            }
            __syncthreads();
            if (pq0 >= 0) {
                int p = pq0 >> 8, q = pq0 & 255;
                if (lane < ns) {
                    float ap = As[lane * 37 + p], aq = As[lane * 37 + q];
                    As[lane * 37 + p] = c0 * ap - s0 * aq;
                    As[lane * 37 + q] = s0 * ap + c0 * aq;
                }
            }
            __syncthreads();
        }
    }

    for (int i = tid; i < ns; i += EIG_T) lam_out[base + i] = As[i * 37 + i];
    for (int t = tid; t < ns * ns; t += EIG_T) {
        int a = t / ns, k = t - (t / ns) * ns;
        Vc[cum2_[s] + t] = Vs[a * 37 + k];
    }
    if (s >= 1) {
        for (int t = tid; t < ns * ksm1; t += EIG_T) {
            int a = t / ksm1, i = t - (t / ksm1) * ksm1;
            int rr = stm1[i];
            float uval = 0.f;
#pragma unroll
            for (int p = 0; p < 7; ++p)
                if (!((rr >> p) & 1)) uval += Vs[a * 37 + inv[rr + (1 << p)]];
            Uc[offsU_[s] + t] = uval;
        }
    }
}

// Compact W + per-entry spectral constants: hl = dLam*DT/2, sigma = rho^4096.
__global__ __launch_bounds__(128) void k_mwc(const float* __restrict__ Vc,
                                             const float* __restrict__ Uc,
                                             const float* __restrict__ lam,
                                             float* __restrict__ wc,
                                             int* __restrict__ ab,
                                             float* __restrict__ hl,
                                             float* __restrict__ sr,
                                             float* __restrict__ si) {
    const int n1_[7]   = {1, 7, 21, 35, 35, 21, 7};
    const int n2_[7]   = {7, 21, 35, 35, 21, 7, 1};
    const int offs_[7] = {0, 7, 154, 889, 2114, 2849, 2996};
    const int nb1_[7]  = {0, 1, 8, 29, 64, 99, 120};
    const int nb2_[7]  = {1, 8, 29, 64, 99, 120, 127};
    const int cum2_[7] = {0, 1, 50, 491, 1716, 2941, 3382};
    int e = blockIdx.x * 128 + threadIdx.x;
    if (e >= 3072) return;
    if (e >= 3003) { wc[e] = 0.f; ab[e] = 0; hl[e] = 0.f; sr[e] = 0.f; si[e] = 0.f; return; }
    int t = 0;
#pragma unroll
    for (int u = 1; u < 7; ++u) if (e >= offs_[u]) t = u;
    int loc = e - offs_[t];
    int n1 = n1_[t], n2 = n2_[t];
    int i = loc / n2;
    int j = loc - i * n2;
    const float* va = &Vc[cum2_[t] + i * n1];
    const float* ub = &Uc[offs_[t] + j * n1];
    float acc = 0.f;
    for (int k = 0; k < n1; ++k) acc += va[k] * ub[k];
    int a = nb1_[t] + i, b = nb2_[t] + j;
    wc[e] = 0.5f * acc * acc;
    ab[e] = (a << 7) | b;
    float dl = lam[a] - lam[b];
    hl[e] = dl * (DT_F * 0.5f);
    const float TT = (float)N_SAMP * DT_F;        // 0.04096
    const float E  = expf(-TT / T2_F);
    float s2, c2;
    sincosf(dl * TT, &s2, &c2);
    sr[e] = E * c2;
    si[e] = E * s2;
}

// Fused tail: blocks 0..511 compute FID (out[0..4096)); blocks 512..1535
// compute closed-form spectrum (32 lanes/k, 8 k/block) + axes.
__global__ __launch_bounds__(256) void k_tail(const float* __restrict__ wc,
                                              const int* __restrict__ ab,
                                              const float* __restrict__ lam,
                                              const float* __restrict__ hl,
                                              const float* __restrict__ sr,
                                              const float* __restrict__ si,
                                              float* __restrict__ out) {
    __shared__ float sww[3072], shl[3072], ssr[3072], ssi[3072];  // 48 KB
    __shared__ float2 cb0[128], dd[128];
    __shared__ float  lred[4][16];
    const int tid = threadIdx.x;

    if (blockIdx.x < 512) {
        // ---------------- FID branch ----------------
        const int n0 = blockIdx.x * 8;
        const float t0 = (float)n0 * DT_F;
        if (tid < 128) {
            float sn, cs;
            sincosf(lam[tid] * t0, &sn, &cs);
            cb0[tid] = make_float2(cs, -sn);
            sincosf(lam[tid] * DT_F, &sn, &cs);
            dd[tid] = make_float2(cs, -sn);
        }
        __syncthreads();

        float ar0=0,ar1=0,ar2=0,ar3=0,ar4=0,ar5=0,ar6=0,ar7=0;
        float ai0=0,ai1=0,ai2=0,ai3=0,ai4=0,ai5=0,ai6=0,ai7=0;
#pragma unroll 4
        for (int i = 0; i < 12; ++i) {
            int e = i * 256 + tid;
            float w = wc[e];
            int pq = ab[e];
            int a = pq >> 7, b = pq & 127;
            float2 ca = cb0[a], cbv = cb0[b];
            float2 da = dd[a],  db  = dd[b];
            float zr = ca.x * cbv.x + ca.y * cbv.y;
            float zi = ca.x * cbv.y - ca.y * cbv.x;
            float fr = da.x * db.x + da.y * db.y;
            float fi = da.x * db.y - da.y * db.x;
            ar0 += w * zr; ai0 += w * zi; { float tr = zr*fr - zi*fi; zi = zr*fi + zi*fr; zr = tr; }
            ar1 += w * zr; ai1 += w * zi; { float tr = zr*fr - zi*fi; zi = zr*fi + zi*fr; zr = tr; }
            ar2 += w * zr; ai2 += w * zi; { float tr = zr*fr - zi*fi; zi = zr*fi + zi*fr; zr = tr; }
            ar3 += w * zr; ai3 += w * zi; { float tr = zr*fr - zi*fi; zi = zr*fi + zi*fr; zr = tr; }
            ar4 += w * zr; ai4 += w * zi; { float tr = zr*fr - zi*fi; zi = zr*fi + zi*fr; zr = tr; }
            ar5 += w * zr; ai5 += w * zi; { float tr = zr*fr - zi*fi; zi = zr*fi + zi*fr; zr = tr; }
            ar6 += w * zr; ai6 += w * zi; { float tr = zr*fr - zi*fi; zi = zr*fi + zi*fr; zr = tr; }
            ar7 += w * zr; ai7 += w * zi;
        }

        const int wave = tid >> 6, lane = tid & 63;
        float acc[16] = {ar0,ai0,ar1,ai1,ar2,ai2,ar3,ai3,ar4,ai4,ar5,ai5,ar6,ai6,ar7,ai7};
#pragma unroll 16
        for (int v = 0; v < 16; ++v) {
            float x = acc[v];
            for (int off = 32; off > 0; off >>= 1) x += __shfl_down(x, off);
            if (lane == 0) lred[wave][v] = x;
        }
        __syncthreads();
        if (tid < 16) {
            float x = lred[0][tid] + lred[1][tid] + lred[2][tid] + lred[3][tid];
            int jj = tid >> 1, c = tid & 1;
            int n = n0 + jj;
            float ap = expf(-(DT_F / T2_F) * (float)n);
            x *= ap;
            if (c == 0) out[n] = x;
        }
    } else {
        // ---------------- spectrum branch ----------------
        const int sb = blockIdx.x - 512;            // 0..1023
        for (int e = tid; e < 3072; e += 256) {
            sww[e] = wc[e]; shl[e] = hl[e]; ssr[e] = sr[e]; ssi[e] = si[e];
        }
        __syncthreads();
        const int kk  = sb * 8 + (tid >> 5);        // 0..8191
        const int l32 = tid & 31;
        const int K   = (kk + 4096) & 8191;
        const float pk  = (3.14159265358979f / 8192.0f) * (float)K;
        const float skf = (K & 1) ? -1.f : 1.f;
        const float A = 9.99995000e-06f;            // 1 - exp(-1e-5)
        const float B = 0.99999000005f;             // exp(-1e-5)
        float acc = 0.f;
        for (int e = l32; e < 3072; e += 32) {
            float ph = shl[e] - pk;
            float sh, ch;
            __sincosf(ph, &sh, &ch);
            float dr = A + 2.f * B * sh * sh;
            float di = -2.f * B * sh * ch;
            float nr = 1.f - skf * ssr[e];
            float ni = -skf * ssi[e];
            float num = nr * dr + ni * di;
            float den = dr * dr + di * di;
            acc += sww[e] * __fdividef(num, den);
        }
#pragma unroll
        for (int off = 16; off > 0; off >>= 1) acc += __shfl_down(acc, off, 32);
        if (l32 == 0) {
            out[8192 + kk] = acc;
            out[16384 + kk] = -0.5f * SW_F + (float)kk * (SW_F / (float)(2 * N_SAMP - 1));
            if (kk < N_SAMP)
                out[4096 + kk] = (float)kk * ((N_SAMP / SW_F) / (float)(N_SAMP - 1));
        }
    }
}

extern "C" void kernel_launch(void* const* d_in, const int* in_sizes, int n_in,
                              void* d_out, int out_size, void* d_ws, size_t ws_size,
                              hipStream_t stream) {
    const float* h = (const float*)d_in[0];
    float* out = (float*)d_out;
    float* ws  = (float*)d_ws;

    float*  Vc   = ws;
    float*  Uc   = ws + 4096;
    float*  lam  = ws + 16384;
    float*  wc   = ws + 49280;
    int*    ab   = (int*)(ws + 52352);
    float*  hl   = ws + 55424;
    float*  sr   = ws + 58496;
    float*  si   = ws + 61568;

    k_eig<<<8, EIG_T, 0, stream>>>(h, Vc, Uc, lam);
    k_mwc<<<24, 128, 0, stream>>>(Vc, Uc, lam, wc, ab, hl, sr, si);
    k_tail<<<1536, 256, 0, stream>>>(wc, ab, lam, hl, sr, si, out);
}

// Round 29
// 57.267 us; speedup vs baseline: 1.7764x; 1.1839x over previous
//
#include <hip/hip_runtime.h>
#include <math.h>

#define N_SAMP 4096
#define NS     7
#define DT_F   1e-5f
#define B0_F   80.0f
#define T2_F   1.0f
#define SW_F   1000.0f
#define TWO_PI 6.2831853071795864769f
#define EIG_T  640   // 10 waves: exactly max pairs/round (C(5,2)=10)

// ws layout (floats): Vc 0..3432 | Uc 4096..7099 | lam 16384..16512 |
//                     wc 49280..52352 | ab(int) 52352..55424 |
//                     fidf(float2) 65664..73856
// out (f32, 24576): ReFID [0,4096) | time [4096,8192) |
//                   Re shifted spec [8192,16384) | freq [16384,24576)

// Sector eigensolver, two-sided Jacobi, sparsity-aware 21-round colored sweep
__global__ __launch_bounds__(EIG_T) void k_eig(const float* __restrict__ h,
                                               float* __restrict__ Vc,
                                               float* __restrict__ Uc,
                                               float* __restrict__ lam_out) {
    const int nsz_[8]   = {1, 7, 21, 35, 35, 21, 7, 1};
    const int nbase_[8] = {0, 1, 8, 29, 64, 99, 120, 127};
    const int cum2_[8]  = {0, 1, 50, 491, 1716, 2941, 3382, 3431};
    const int offsU_[8] = {0, 0, 7, 154, 889, 2114, 2849, 2996}; // s>=1
    const int s    = blockIdx.x;
    const int ns   = nsz_[s];
    const int base = nbase_[s];
    const int tid  = threadIdx.x;
    const int wave = tid >> 6;
    const int lane = tid & 63;

    __shared__ float As[36 * 37];
    __shared__ float Vs[36 * 37];
    __shared__ int   st[36];
    __shared__ int   stm1[36];
    __shared__ int   inv[128];
    __shared__ float hs[49];
    __shared__ int   ppt2[21 * 12];
    __shared__ int   cnt2[21];

    const int ksm1 = (s >= 1) ? nsz_[s - 1] : 0;

    if (tid < 49) hs[tid] = h[tid];
    if (tid < 21) cnt2[tid] = 0;
    if (tid == 0) {
        int cnt = 0;
        for (int r = 0; r < 128; ++r) if (__popc(r) == s) st[cnt++] = r;
    }
    if (tid == 1 && s >= 1) {
        int cnt = 0;
        for (int r = 0; r < 128; ++r) if (__popc(r) == s - 1) stm1[cnt++] = r;
    }
    if (tid < 128 && __popc(tid) == s) {
        int cnt = 0;
        for (int r = 0; r < 128; ++r) { if (r == tid) break; if (__popc(r) == s) ++cnt; }
        inv[tid] = cnt;
    }
    for (int t = tid; t < 36 * 37; t += EIG_T) { As[t] = 0.f; Vs[t] = 0.f; }
    __syncthreads();

    if (ns > 1) {
        const int off_[7] = {0, 6, 11, 15, 18, 20, 0};
        for (int r = tid; r < 128; r += EIG_T) {
            if (__popc(r) == s) {
                for (int i = 0; i < 6; ++i) {
                    if (!((r >> i) & 1)) continue;
                    for (int j = i + 1; j < 7; ++j) {
                        if ((r >> j) & 1) continue;
                        int rid = off_[i] + (j - i - 1);
                        int prt = r ^ ((1 << i) | (1 << j));
                        int slot = atomicAdd(&cnt2[rid], 1);
                        ppt2[rid * 12 + slot] = (inv[r] << 8) | inv[prt];
                    }
                }
            }
        }
    }

    for (int t = tid; t < ns * ns; t += EIG_T) {
        int i = t / ns, j = t % ns;
        int r = st[i], c = st[j];
        float val = 0.f;
        if (r == c) {
            float acc = 0.f;
            for (int a = 0; a < 7; ++a) {
                float za = ((r >> (6 - a)) & 1) ? -0.5f : 0.5f;
                acc += B0_F * hs[a * 7 + a] * za;
                for (int b = a + 1; b < 7; ++b) {
                    float zb = ((r >> (6 - b)) & 1) ? -0.5f : 0.5f;
                    acc += hs[a * 7 + b] * za * zb;
                }
            }
            val = TWO_PI * acc;
        } else {
            int x = r ^ c;
            if (__popc(x) == 2) {
                int u = 31 - __clz(x);
                int v = __ffs(x) - 1;
                if (((r >> u) & 1) != ((r >> v) & 1))
                    val = TWO_PI * 0.5f * hs[(6 - u) * 7 + (6 - v)];
            }
        }
        As[i * 37 + j] = val;
    }
    for (int i = tid; i < ns; i += EIG_T) Vs[i * 37 + i] = 1.f;
    __syncthreads();

    if (ns > 1) {
        for (int t = 0; t < 21; ++t) {
            int npr = cnt2[t];
            float c0 = 1.f, s0 = 0.f;
            int   pq0 = -1;
            if (wave < npr) {
                int pq = ppt2[t * 12 + wave];
                int p = pq >> 8, q = pq & 255;
                float app = As[p * 37 + p];
                float aqq = As[q * 37 + q];
                float apq = As[p * 37 + q];
                float c = 1.f, sn = 0.f;
                if (fabsf(apq) >= 1e-30f) {
                    float tau = (aqq - app) / (2.f * apq);
                    float tt  = copysignf(1.f / (fabsf(tau) + sqrtf(1.f + tau * tau)), tau);
                    c  = rsqrtf(1.f + tt * tt);
                    sn = tt * c;
                }
                c0 = c; s0 = sn; pq0 = pq;
                if (lane < ns) {
                    float ap = As[p * 37 + lane], aq = As[q * 37 + lane];
                    As[p * 37 + lane] = c * ap - sn * aq;
                    As[q * 37 + lane] = sn * ap + c * aq;
                    float vp = Vs[p * 37 + lane], vq = Vs[q * 37 + lane];
                    Vs[p * 37 + lane] = c * vp - sn * vq;
                    Vs[q * 37 + lane] = sn * vp + c * vq;
                }
            }
            __syncthreads();
            if (pq0 >= 0) {
                int p = pq0 >> 8, q = pq0 & 255;
                if (lane < ns) {
                    float ap = As[lane * 37 + p], aq = As[lane * 37 + q];
                    As[lane * 37 + p] = c0 * ap - s0 * aq;
                    As[lane * 37 + q] = s0 * ap + c0 * aq;
                }
            }
            __syncthreads();
        }
    }

    for (int i = tid; i < ns; i += EIG_T) lam_out[base + i] = As[i * 37 + i];
    for (int t = tid; t < ns * ns; t += EIG_T) {
        int a = t / ns, k = t - (t / ns) * ns;
        Vc[cum2_[s] + t] = Vs[a * 37 + k];
    }
    if (s >= 1) {
        for (int t = tid; t < ns * ksm1; t += EIG_T) {
            int a = t / ksm1, i = t - (t / ksm1) * ksm1;
            int rr = stm1[i];
            float uval = 0.f;
#pragma unroll
            for (int p = 0; p < 7; ++p)
                if (!((rr >> p) & 1)) uval += Vs[a * 37 + inv[rr + (1 << p)]];
            Uc[offsU_[s] + t] = uval;
        }
    }
}

// Compact W from compact Vc/Uc + zero spec region + write time/freq axes.
__global__ __launch_bounds__(128) void k_mwc(const float* __restrict__ Vc,
                                             const float* __restrict__ Uc,
                                             float* __restrict__ wc,
                                             int* __restrict__ ab,
                                             float* __restrict__ out) {
    const int n1_[7]   = {1, 7, 21, 35, 35, 21, 7};
    const int n2_[7]   = {7, 21, 35, 35, 21, 7, 1};
    const int offs_[7] = {0, 7, 154, 889, 2114, 2849, 2996};
    const int nb1_[7]  = {0, 1, 8, 29, 64, 99, 120};
    const int nb2_[7]  = {1, 8, 29, 64, 99, 120, 127};
    const int cum2_[7] = {0, 1, 50, 491, 1716, 2941, 3382};
    int e = blockIdx.x * 128 + threadIdx.x;   // 0..3071

    // aux: zero spec chunk (atomic k_dft accumulates later) + axes
    for (int i = e; i < 8192; i += 3072) {
        out[8192 + i] = 0.f;
        out[16384 + i] = -0.5f * SW_F + (float)i * (SW_F / (float)(2 * N_SAMP - 1));
        if (i < N_SAMP)
            out[4096 + i] = (float)i * ((N_SAMP / SW_F) / (float)(N_SAMP - 1));
    }

    if (e >= 3072) return;
    if (e >= 3003) { wc[e] = 0.f; ab[e] = 0; return; }
    int t = 0;
#pragma unroll
    for (int u = 1; u < 7; ++u) if (e >= offs_[u]) t = u;
    int loc = e - offs_[t];
    int n1 = n1_[t], n2 = n2_[t];
    int i = loc / n2;
    int j = loc - i * n2;
    const float* va = &Vc[cum2_[t] + i * n1];
    const float* ub = &Uc[offs_[t] + j * n1];
    float acc = 0.f;
    for (int k = 0; k < n1; ++k) acc += va[k] * ub[k];
    wc[e] = 0.5f * acc * acc;
    ab[e] = ((nb1_[t] + i) << 7) | (nb2_[t] + j);
}

// 8 samples per block via phasor recurrence over the 3072 compact entries
__global__ __launch_bounds__(256) void k_fid(const float* __restrict__ wc,
                                             const int* __restrict__ ab,
                                             const float* __restrict__ lam,
                                             float* __restrict__ fidfF,
                                             float* __restrict__ out) {
    __shared__ float2 cb0[128], dd[128];
    __shared__ float  lred[4][16];
    const int n0  = blockIdx.x * 8;
    const int tid = threadIdx.x;
    const float t0 = (float)n0 * DT_F;
    if (tid < 128) {
        float sn, cs;
        sincosf(lam[tid] * t0, &sn, &cs);
        cb0[tid] = make_float2(cs, -sn);
        sincosf(lam[tid] * DT_F, &sn, &cs);
        dd[tid] = make_float2(cs, -sn);
    }
    __syncthreads();

    float ar0=0,ar1=0,ar2=0,ar3=0,ar4=0,ar5=0,ar6=0,ar7=0;
    float ai0=0,ai1=0,ai2=0,ai3=0,ai4=0,ai5=0,ai6=0,ai7=0;
#pragma unroll 4
    for (int i = 0; i < 12; ++i) {
        int e = i * 256 + tid;
        float w = wc[e];
        int pq = ab[e];
        int a = pq >> 7, b = pq & 127;
        float2 ca = cb0[a], cbv = cb0[b];
        float2 da = dd[a],  db  = dd[b];
        float zr = ca.x * cbv.x + ca.y * cbv.y;
        float zi = ca.x * cbv.y - ca.y * cbv.x;
        float fr = da.x * db.x + da.y * db.y;
        float fi = da.x * db.y - da.y * db.x;
        ar0 += w * zr; ai0 += w * zi; { float tr = zr*fr - zi*fi; zi = zr*fi + zi*fr; zr = tr; }
        ar1 += w * zr; ai1 += w * zi; { float tr = zr*fr - zi*fi; zi = zr*fi + zi*fr; zr = tr; }
        ar2 += w * zr; ai2 += w * zi; { float tr = zr*fr - zi*fi; zi = zr*fi + zi*fr; zr = tr; }
        ar3 += w * zr; ai3 += w * zi; { float tr = zr*fr - zi*fi; zi = zr*fi + zi*fr; zr = tr; }
        ar4 += w * zr; ai4 += w * zi; { float tr = zr*fr - zi*fi; zi = zr*fi + zi*fr; zr = tr; }
        ar5 += w * zr; ai5 += w * zi; { float tr = zr*fr - zi*fi; zi = zr*fi + zi*fr; zr = tr; }
        ar6 += w * zr; ai6 += w * zi; { float tr = zr*fr - zi*fi; zi = zr*fi + zi*fr; zr = tr; }
        ar7 += w * zr; ai7 += w * zi;
    }

    const int wave = tid >> 6, lane = tid & 63;
    float acc[16] = {ar0,ai0,ar1,ai1,ar2,ai2,ar3,ai3,ar4,ai4,ar5,ai5,ar6,ai6,ar7,ai7};
#pragma unroll 16
    for (int v = 0; v < 16; ++v) {
        float x = acc[v];
        for (int off = 32; off > 0; off >>= 1) x += __shfl_down(x, off);
        if (lane == 0) lred[wave][v] = x;
    }
    __syncthreads();
    if (tid < 16) {
        float x = lred[0][tid] + lred[1][tid] + lred[2][tid] + lred[3][tid];
        int jj = tid >> 1, c = tid & 1;
        int n = n0 + jj;
        float ap = expf(-(DT_F / T2_F) * (float)n);
        x *= ap;
        fidfF[2 * n + c] = x;
        if (c == 0) out[n] = x;
    }
}

// split-K shifted-spectrum: 16 chunks x 32 k-groups; phasor recurrence;
// partials accumulated straight into out via atomicAdd (spec pre-zeroed).
__global__ __launch_bounds__(256) void k_dft(const float2* __restrict__ fidf,
                                             float* __restrict__ out) {
    __shared__ float2 fsh[256];
    const int tid = threadIdx.x;
    const int ch  = blockIdx.x >> 5;
    const int kb  = blockIdx.x & 31;
    const int n0  = ch * 256;
    fsh[tid] = fidf[n0 + tid];
    __syncthreads();
    const int k = kb * 256 + tid;
    const int K = (k + 4096) & 8191;
    const float C = TWO_PI / 8192.0f;
    float zs, zc, fs_, fc;
    __sincosf(C * (float)((n0 * K) & 8191), &zs, &zc);
    __sincosf(C * (float)K, &fs_, &fc);
    float ar = 0.f;
    for (int i = 0; i < 256; ++i) {
        float2 s = fsh[i];
        ar += s.x * zc + s.y * zs;
        float t = zc * fc - zs * fs_;
        zs = zc * fs_ + zs * fc;
        zc = t;
    }
    atomicAdd(&out[8192 + k], ar);
}

extern "C" void kernel_launch(void* const* d_in, const int* in_sizes, int n_in,
                              void* d_out, int out_size, void* d_ws, size_t ws_size,
                              hipStream_t stream) {
    const float* h = (const float*)d_in[0];
    float* out = (float*)d_out;
    float* ws  = (float*)d_ws;

    float*  Vc   = ws;
    float*  Uc   = ws + 4096;
    float*  lam  = ws + 16384;
    float*  wc   = ws + 49280;
    int*    ab   = (int*)(ws + 52352);
    float*  fidfF= ws + 65664;
    float2* fidf = (float2*)(ws + 65664);

    k_eig<<<8, EIG_T, 0, stream>>>(h, Vc, Uc, lam);
    k_mwc<<<24, 128, 0, stream>>>(Vc, Uc, wc, ab, out);
    k_fid<<<512, 256, 0, stream>>>(wc, ab, lam, fidfF, out);
    k_dft<<<512, 256, 0, stream>>>(fidf, out);
}